// Round 4
// baseline (527.208 us; speedup 1.0000x reference)
//
#include <hip/hip_runtime.h>
#include <cstdint>
#include <cstddef>

// Problem constants (from reference setup_inputs)
#define BN 16     // batch
#define CC 256    // channels
#define CKD 32    // q/k channels
#define NN 4096   // H*W

typedef __attribute__((ext_vector_type(8))) short s8v;    // 8 bf16 = 4 VGPRs (MFMA A/B frag)
typedef __attribute__((ext_vector_type(4))) float f4v;    // MFMA C/D frag
typedef __attribute__((ext_vector_type(4))) unsigned int u4v;
typedef __attribute__((ext_vector_type(2))) unsigned int u2v;
typedef unsigned short ushort_t;

#define L2E 1.44269504088896340736f

__device__ __forceinline__ ushort_t f2bf(float f) {
    union { float f; uint32_t u; } v; v.f = f;
    uint32_t u = v.u + 0x7FFFu + ((v.u >> 16) & 1u);  // RNE
    return (ushort_t)(u >> 16);
}
__device__ __forceinline__ uint32_t fbits(float f) {
    union { float f; uint32_t u; } v; v.f = f; return v.u;
}
// raw v_exp_f32: computes 2^x (q is pre-scaled by log2e in proj)
__device__ __forceinline__ float exp2_hw(float x) {
    float r; asm("v_exp_f32 %0, %1" : "=v"(r) : "v"(x)); return r;
}
// pack two floats to (bf16(lo) | bf16(hi)<<16), truncation
__device__ __forceinline__ uint32_t pkbf(float lo, float hi) {
    return __builtin_amdgcn_perm(fbits(hi), fbits(lo), 0x07060302u);
}

// ---------------- fused q/k/v projection as one MFMA GEMM ----------------
// v5: 1-D grid with XCD-affinity swizzle -- the 5 m-tile blocks sharing one (b, n-strip)
// x slice (128 KB) are placed adjacently on the SAME XCD, so x is fetched from HBM once
// and re-read 4x from that XCD's L2 (was: 5x redundant HBM reads = 640 MB, proj's pole).
__global__ __launch_bounds__(256) void proj_all(
    const float* __restrict__ x,
    const float* __restrict__ Wq, const float* __restrict__ bq,
    const float* __restrict__ Wk, const float* __restrict__ bk,
    const float* __restrict__ Wv, const float* __restrict__ bv,
    ushort_t* __restrict__ qw, ushort_t* __restrict__ kw, ushort_t* __restrict__ vw)
{
    __shared__ __align__(16) ushort_t As[64 * 264];

    // decode swizzled block id: XCD = l%8; per-XCD order = (slot, m) lexicographic, so the
    // 5 m-tiles of one (b,n) group are co-resident on one XCD.
    int l = blockIdx.x;
    int xcd = l & 7;
    int t = l >> 3;               // 0..319
    int slot = t / 5;             // 0..63
    int mten = t - slot * 5;      // 0..4
    int p = slot * 8 + xcd;       // 0..511 = b*32 + n
    int b  = p >> 5;
    int m0 = mten * 64;
    int n0 = (p & 31) * 128;

    int tid = threadIdx.x;
    int wave = tid >> 6, lane = tid & 63;
    int lq = lane & 15, quad = lane >> 4;

    {
        int arow = tid >> 2;
        int kseg = (tid & 3) * 64;
        int am = m0 + arow;
        const float* wrow;
        if (am < 32)       wrow = Wq + (size_t)am * CC;
        else if (am < 64)  wrow = Wk + (size_t)(am - 32) * CC;
        else               wrow = Wv + (size_t)(am - 64) * CC;
#pragma unroll
        for (int g = 0; g < 8; g++) {
            f4v f0 = *reinterpret_cast<const f4v*>(wrow + kseg + g * 8);
            f4v f1 = *reinterpret_cast<const f4v*>(wrow + kseg + g * 8 + 4);
            s8v p2;
            p2[0] = (short)f2bf(f0[0]); p2[1] = (short)f2bf(f0[1]);
            p2[2] = (short)f2bf(f0[2]); p2[3] = (short)f2bf(f0[3]);
            p2[4] = (short)f2bf(f1[0]); p2[5] = (short)f2bf(f1[1]);
            p2[6] = (short)f2bf(f1[2]); p2[7] = (short)f2bf(f1[3]);
            *reinterpret_cast<s8v*>(&As[arow * 264 + kseg + g * 8]) = p2;
        }
    }
    __syncthreads();

    f4v acc[4][2];
#pragma unroll
    for (int i = 0; i < 4; i++)
#pragma unroll
        for (int j = 0; j < 2; j++) acc[i][j] = (f4v){0.f, 0.f, 0.f, 0.f};

    const float* xb = x + (size_t)b * CC * NN + n0 + wave * 32 + lq;

#pragma unroll 2
    for (int h = 0; h < 8; h++) {
        s8v bb[2];
#pragma unroll
        for (int nt = 0; nt < 2; nt++) {
            const float* src = xb + (size_t)(h * 32 + quad * 8) * NN + nt * 16;
            float t0 = src[0 * NN];
            float t1 = src[1 * NN];
            float t2 = src[2 * NN];
            float t3 = src[3 * NN];
            float t4 = src[4 * NN];
            float t5 = src[5 * NN];
            float t6 = src[6 * NN];
            float t7 = src[7 * NN];
            s8v p2;
            p2[0] = (short)f2bf(t0); p2[1] = (short)f2bf(t1);
            p2[2] = (short)f2bf(t2); p2[3] = (short)f2bf(t3);
            p2[4] = (short)f2bf(t4); p2[5] = (short)f2bf(t5);
            p2[6] = (short)f2bf(t6); p2[7] = (short)f2bf(t7);
            bb[nt] = p2;
        }
        s8v a[4];
#pragma unroll
        for (int mt = 0; mt < 4; mt++)
            a[mt] = *reinterpret_cast<const s8v*>(
                &As[(mt * 16 + lq) * 264 + h * 32 + quad * 8]);
#pragma unroll
        for (int mt = 0; mt < 4; mt++)
#pragma unroll
            for (int nt = 0; nt < 2; nt++)
                acc[mt][nt] = __builtin_amdgcn_mfma_f32_16x16x32_bf16(
                    a[mt], bb[nt], acc[mt][nt], 0, 0, 0);
    }

#pragma unroll
    for (int mt = 0; mt < 4; mt++) {
#pragma unroll
        for (int r = 0; r < 4; r++) {
            int mm = m0 + mt * 16 + quad * 4 + r;
            float bias = (mm < 32) ? bq[mm] : (mm < 64 ? bk[mm - 32] : bv[mm - 64]);
#pragma unroll
            for (int nt = 0; nt < 2; nt++) {
                int n = n0 + wave * 32 + nt * 16 + lq;
                float val = acc[mt][nt][r] + bias;
                if (mm < 32) val *= L2E;
                ushort_t obf = f2bf(val);
                if (mm < 32)
                    qw[((size_t)b * NN + n) * CKD + mm] = obf;
                else if (mm < 64)
                    kw[((size_t)b * NN + n) * CKD + (mm - 32)] = obf;
                else
                    vw[((size_t)b * CC + (mm - 64)) * NN + n] = obf;
            }
        }
    }
}

// ---------------- flash attention v5: DS-pipe-minimal + XCD batch affinity ----------------
// v4 post-mortem: DS pipe was the pole (360 KB/kt-CU: P broadcast 128 KB + K 32 KB + writes),
// plus an 8-way bank conflict on the permuted K-frag reads (2.1e7 conflict cycles).
// v5:
//  (a) Kl stride 32 -> 36 shorts: K-frag bank = (18*kidx+4*quad)%32, max 2-way (free).
//  (b) PV wave-split 64q x 64c (was 128q x 32c): each wave reads HALF of P -> P DS-read
//      64 KB/block-kt; total DS 232 KB/kt-CU. V frag loads double (8 b128/wave) but hit L2.
//  (c) XCD batch affinity: batch b's 32 q-tile blocks all on XCD b%8. All blocks sweep the
//      SAME 32 KB V-window per kt -> one L3->L2 fill per window instead of 8.
// grid 512 1-D, block 512 = 8 waves; wave wq: softmax rows [wq*16,+16), PV slice
// (q-half i=wq>>2) x (chan-quarter j=wq&3).
__global__ __launch_bounds__(512, 4) void attn(
    const ushort_t* __restrict__ qw, const ushort_t* __restrict__ kw,
    const ushort_t* __restrict__ vw, const float* __restrict__ x,
    const float* __restrict__ alpha, float* __restrict__ out)
{
    __shared__ __align__(16) ushort_t Pl[2][128 * 72];   // 36,864 B  P double buffer
    __shared__ __align__(16) ushort_t Kl[2][64 * 36];    //  9,216 B  K tile double buffer (padded)
    __shared__ float lL[128];                            // row denominators

    // XCD-affinity decode: b = (l&7) + 8*bit3(l) -> XCD(l)=l%8 = b%8
    int l = blockIdx.x;
    int b = (l & 7) | (((l >> 3) & 1) << 3);
    int q0 = (l >> 4) * 128;

    int tid = threadIdx.x;
    int wq = tid >> 6, lane = tid & 63;
    int lq = lane & 15, quad = lane >> 4;
    int i64 = (wq >> 2) * 64;     // PV q-half base
    int j64 = (wq & 3) * 64;      // PV chan-quarter base

    const ushort_t* kbase = kw + (size_t)b * NN * CKD;
    const ushort_t* vbase = vw + (size_t)b * CC * NN;

    // K staging assignment: thread stages 8B of row krow at col kcol
    int krow = tid >> 3;            // 0..63
    int kcol = (tid & 7) * 4;       // shorts
    const ushort_t* ksrc = kbase + (size_t)krow * CKD + kcol;

    // permuted K-row frag offsets in Kl (shorts, stride 36): kidx = 32(nt>>1)+2(lq&12)+4(nt&1)+(lq&3)
    int kro[4];
#pragma unroll
    for (int nt = 0; nt < 4; nt++)
        kro[nt] = (32 * (nt >> 1) + 2 * (lq & 12) + 4 * (nt & 1) + (lq & 3)) * 36 + quad * 8;

    // V slice rows for this wave: c = j64 + ct*16 + lq
    const ushort_t* vr[4];
#pragma unroll
    for (int ct = 0; ct < 4; ct++)
        vr[ct] = vbase + (size_t)(j64 + ct * 16 + lq) * NN;

    // Q B-fragment for this wave's 16 softmax rows
    const s8v qf = *reinterpret_cast<const s8v*>(
        qw + ((size_t)b * NN + q0 + wq * 16 + lq) * CKD + quad * 8);

    f4v acc[4][4];
#pragma unroll
    for (int i = 0; i < 4; i++)
#pragma unroll
        for (int j = 0; j < 4; j++) acc[i][j] = (f4v){0.f, 0.f, 0.f, 0.f};
    float srow = 0.f;

    // ---- prologue: stage K[0],K[1]; prefetch K[2] + V[0] frags ----
    u2v k0 = *reinterpret_cast<const u2v*>(ksrc);
    u2v k1 = *reinterpret_cast<const u2v*>(ksrc + (size_t)64 * CKD);
    u2v kst = *reinterpret_cast<const u2v*>(ksrc + (size_t)128 * CKD);
    s8v vv[4][2];
#pragma unroll
    for (int ct = 0; ct < 4; ct++) {
        vv[ct][0] = *reinterpret_cast<const s8v*>(vr[ct] + quad * 8);
        vv[ct][1] = *reinterpret_cast<const s8v*>(vr[ct] + 32 + quad * 8);
    }
    *reinterpret_cast<u2v*>(&Kl[0][krow * 36 + kcol]) = k0;
    *reinterpret_cast<u2v*>(&Kl[1][krow * 36 + kcol]) = k1;
    __syncthreads();

    for (int kt = 0; kt < 64; kt++) {
        const int cur = kt & 1;

        // ---- QK^T from Kl[cur]; P in-register via permuted rows (v3-verified) ----
        s8v pa0, pa1;
        {
            s8v kf0 = *reinterpret_cast<const s8v*>(&Kl[cur][kro[0]]);
            s8v kf1 = *reinterpret_cast<const s8v*>(&Kl[cur][kro[1]]);
            f4v sA = __builtin_amdgcn_mfma_f32_16x16x32_bf16(kf0, qf, (f4v){0.f,0.f,0.f,0.f}, 0, 0, 0);
            f4v sB = __builtin_amdgcn_mfma_f32_16x16x32_bf16(kf1, qf, (f4v){0.f,0.f,0.f,0.f}, 0, 0, 0);
            s8v kf2 = *reinterpret_cast<const s8v*>(&Kl[cur][kro[2]]);
            s8v kf3 = *reinterpret_cast<const s8v*>(&Kl[cur][kro[3]]);
            f4v sC = __builtin_amdgcn_mfma_f32_16x16x32_bf16(kf2, qf, (f4v){0.f,0.f,0.f,0.f}, 0, 0, 0);
            f4v sD = __builtin_amdgcn_mfma_f32_16x16x32_bf16(kf3, qf, (f4v){0.f,0.f,0.f,0.f}, 0, 0, 0);
            float a0 = exp2_hw(sA[0]), a1 = exp2_hw(sA[1]), a2 = exp2_hw(sA[2]), a3 = exp2_hw(sA[3]);
            float b0 = exp2_hw(sB[0]), b1 = exp2_hw(sB[1]), b2 = exp2_hw(sB[2]), b3 = exp2_hw(sB[3]);
            srow += ((a0 + a1) + (a2 + a3)) + ((b0 + b1) + (b2 + b3));
            union { u4v u; s8v s; } t0;
            t0.u[0] = pkbf(a0, a1); t0.u[1] = pkbf(a2, a3);
            t0.u[2] = pkbf(b0, b1); t0.u[3] = pkbf(b2, b3);
            pa0 = t0.s;
            float c0 = exp2_hw(sC[0]), c1 = exp2_hw(sC[1]), c2 = exp2_hw(sC[2]), c3 = exp2_hw(sC[3]);
            float d0 = exp2_hw(sD[0]), d1 = exp2_hw(sD[1]), d2 = exp2_hw(sD[2]), d3 = exp2_hw(sD[3]);
            srow += ((c0 + c1) + (c2 + c3)) + ((d0 + d1) + (d2 + d3));
            union { u4v u; s8v s; } t1;
            t1.u[0] = pkbf(c0, c1); t1.u[1] = pkbf(c2, c3);
            t1.u[2] = pkbf(d0, d1); t1.u[3] = pkbf(d2, d3);
            pa1 = t1.s;
        }

        // publish P (same (row,col) the A-frag reads use -> identity round-trip)
        {
            int prow = (wq * 16 + lq) * 72;
            *reinterpret_cast<s8v*>(&Pl[cur][prow + quad * 8]) = pa0;
            *reinterpret_cast<s8v*>(&Pl[cur][prow + 32 + quad * 8]) = pa1;
        }

        __syncthreads();
        __builtin_amdgcn_sched_barrier(0);

        // stage K[kt+2] -> Kl[cur] (reads of Kl[cur] finished pre-barrier; next read kt+2)
        *reinterpret_cast<u2v*>(&Kl[cur][krow * 36 + kcol]) = kst;

        // ---- PV: O += P V^T over this wave's (64 q) x (64 c) tile ----
        __builtin_amdgcn_s_setprio(1);
#pragma unroll
        for (int qt = 0; qt < 4; qt++) {
            int pr = (i64 + qt * 16 + lq) * 72;
            s8v pA0 = *reinterpret_cast<const s8v*>(&Pl[cur][pr + quad * 8]);
            s8v pA1 = *reinterpret_cast<const s8v*>(&Pl[cur][pr + 32 + quad * 8]);
#pragma unroll
            for (int ct = 0; ct < 4; ct++) {
                acc[qt][ct] = __builtin_amdgcn_mfma_f32_16x16x32_bf16(pA0, vv[ct][0], acc[qt][ct], 0, 0, 0);
                acc[qt][ct] = __builtin_amdgcn_mfma_f32_16x16x32_bf16(pA1, vv[ct][1], acc[qt][ct], 0, 0, 0);
            }
        }
        __builtin_amdgcn_s_setprio(0);

        // ---- next-tile loads (cover: next QK+exp+P-write+barrier) ----
        {
            int kbn = (kt + 1 < 64 ? kt + 1 : 63) * 64;
#pragma unroll
            for (int ct = 0; ct < 4; ct++) {
                vv[ct][0] = *reinterpret_cast<const s8v*>(vr[ct] + kbn + quad * 8);
                vv[ct][1] = *reinterpret_cast<const s8v*>(vr[ct] + kbn + 32 + quad * 8);
            }
            int kn = (kt + 3 < 64 ? kt + 3 : 63) * 64;
            kst = *reinterpret_cast<const u2v*>(ksrc + (size_t)kn * CKD);
        }
    }

    // ---- row sums: reduce across quads; share per-wave via LDS ----
    srow += __shfl_xor(srow, 16, 64);
    srow += __shfl_xor(srow, 32, 64);
    if (quad == 0) lL[wq * 16 + lq] = srow;
    __syncthreads();

    // ---- epilogue: out = alpha * (O / l) + x ----
    float a0 = alpha[0];
#pragma unroll
    for (int qt = 0; qt < 4; qt++) {
        float li[4];
#pragma unroll
        for (int r = 0; r < 4; r++) li[r] = 1.0f / lL[i64 + qt * 16 + quad * 4 + r];
#pragma unroll
        for (int ct = 0; ct < 4; ct++) {
            int c = j64 + ct * 16 + lq;
            size_t idx = ((size_t)b * CC + c) * NN + q0 + i64 + qt * 16 + quad * 4;
            f4v xv = *reinterpret_cast<const f4v*>(x + idx);
            f4v o;
#pragma unroll
            for (int r = 0; r < 4; r++) o[r] = a0 * (acc[qt][ct][r] * li[r]) + xv[r];
            *reinterpret_cast<f4v*>(out + idx) = o;
        }
    }
}

extern "C" void kernel_launch(void* const* d_in, const int* in_sizes, int n_in,
                              void* d_out, int out_size, void* d_ws, size_t ws_size,
                              hipStream_t stream) {
    (void)in_sizes; (void)n_in; (void)out_size; (void)ws_size;
    const float* x     = (const float*)d_in[0];
    const float* Wq    = (const float*)d_in[1];
    const float* bq    = (const float*)d_in[2];
    const float* Wk    = (const float*)d_in[3];
    const float* bk    = (const float*)d_in[4];
    const float* Wv    = (const float*)d_in[5];
    const float* bv    = (const float*)d_in[6];
    const float* alpha = (const float*)d_in[7];
    float* out = (float*)d_out;

    // Workspace: q (4MB) | k (4MB) | v (32MB), all bf16
    char* ws = (char*)d_ws;
    ushort_t* qw = (ushort_t*)ws;
    ushort_t* kw = (ushort_t*)(ws + (size_t)BN * NN * CKD * 2);
    ushort_t* vw = (ushort_t*)(ws + (size_t)2 * BN * NN * CKD * 2);

    proj_all<<<dim3(2560), 256, 0, stream>>>(x, Wq, bq, Wk, bk, Wv, bv, qw, kw, vw);
    attn    <<<dim3(512), 512, 0, stream>>>(qw, kw, vw, x, alpha, out);
}

// Round 5
// 318.769 us; speedup vs baseline: 1.6539x; 1.6539x over previous
//
#include <hip/hip_runtime.h>
#include <cstdint>
#include <cstddef>

// Problem constants (from reference setup_inputs)
#define BN 16     // batch
#define CC 256    // channels
#define CKD 32    // q/k channels
#define NN 4096   // H*W

typedef __attribute__((ext_vector_type(8))) short s8v;    // 8 bf16 = 4 VGPRs (MFMA A/B frag)
typedef __attribute__((ext_vector_type(4))) float f4v;    // MFMA C/D frag
typedef __attribute__((ext_vector_type(4))) unsigned int u4v;
typedef __attribute__((ext_vector_type(2))) unsigned int u2v;
typedef unsigned short ushort_t;

#define L2E 1.44269504088896340736f

__device__ __forceinline__ ushort_t f2bf(float f) {
    union { float f; uint32_t u; } v; v.f = f;
    uint32_t u = v.u + 0x7FFFu + ((v.u >> 16) & 1u);  // RNE
    return (ushort_t)(u >> 16);
}
__device__ __forceinline__ uint32_t fbits(float f) {
    union { float f; uint32_t u; } v; v.f = f; return v.u;
}
// raw v_exp_f32: computes 2^x (q is pre-scaled by log2e in proj)
__device__ __forceinline__ float exp2_hw(float x) {
    float r; asm("v_exp_f32 %0, %1" : "=v"(r) : "v"(x)); return r;
}
// pack two floats to (bf16(lo) | bf16(hi)<<16), truncation (P only)
__device__ __forceinline__ uint32_t pkbf(float lo, float hi) {
    return __builtin_amdgcn_perm(fbits(hi), fbits(lo), 0x07060302u);
}
// RNE pack of two floats into one dword of 2 bf16
__device__ __forceinline__ uint32_t pkbf_rne(float lo, float hi) {
    return (uint32_t)f2bf(lo) | ((uint32_t)f2bf(hi) << 16);
}

// ---------------- fused q/k/v projection, v6: x read ONCE per block ----------------
// v5 post-mortem: proj was flat (~140 us) across all LDS/affinity changes. Invariant cost:
// the 5 m-tile blocks each re-read AND re-convert the same x strip (5x fabric, 5x f2bf),
// and q/k epilogue wrote 2B scatters at 64B stride (32x write amplification).
// v6: ONE block owns a 64-n strip and loops over all 5 m-tiles. B-fragments (x) load into
// 32 VGPRs once and are reused across passes; only the 32 KB W tile re-stages per pass.
// q/k writes become packed b64 stores of 4 consecutive channels (fully coalesced).
// grid (64, 16), block 256 = 4 waves (wave w owns n sub-range w*16); 4 blocks/CU.
__global__ __launch_bounds__(256) void proj_all(
    const float* __restrict__ x,
    const float* __restrict__ Wq, const float* __restrict__ bq,
    const float* __restrict__ Wk, const float* __restrict__ bk,
    const float* __restrict__ Wv, const float* __restrict__ bv,
    ushort_t* __restrict__ qw, ushort_t* __restrict__ kw, ushort_t* __restrict__ vw)
{
    __shared__ __align__(16) ushort_t As[64 * 264];   // W tile: 64 rows x 256 k, stride 264

    int b  = blockIdx.y;
    int n0 = blockIdx.x * 64;
    int tid = threadIdx.x;
    int wave = tid >> 6, lane = tid & 63;
    int lq = lane & 15, quad = lane >> 4;
    int n = n0 + wave * 16 + lq;

    // ---- B-fragments: load x ONCE (64 scalar f32, 64B-coalesced per 16-lane group) ----
    const float* xb = x + (size_t)b * CC * NN + n;
    s8v bb[8];
#pragma unroll
    for (int h = 0; h < 8; h++) {
        const float* src = xb + (size_t)(h * 32 + quad * 8) * NN;
        float t0 = src[0 * NN];
        float t1 = src[1 * NN];
        float t2 = src[2 * NN];
        float t3 = src[3 * NN];
        float t4 = src[4 * NN];
        float t5 = src[5 * NN];
        float t6 = src[6 * NN];
        float t7 = src[7 * NN];
        s8v p;
        p[0] = (short)f2bf(t0); p[1] = (short)f2bf(t1);
        p[2] = (short)f2bf(t2); p[3] = (short)f2bf(t3);
        p[4] = (short)f2bf(t4); p[5] = (short)f2bf(t5);
        p[6] = (short)f2bf(t6); p[7] = (short)f2bf(t7);
        bb[h] = p;
    }

    // A-staging assignment (per pass): 4 threads per row, 64 floats each
    int arow = tid >> 2;
    int kseg = (tid & 3) * 64;

    for (int mten = 0; mten < 5; mten++) {
        int m0 = mten * 64;
        __syncthreads();   // previous pass's As readers done

        // ---- stage W rows [m0, m0+64) -> As (b128 writes) ----
        {
            int am = m0 + arow;
            const float* wrow;
            if (am < 32)       wrow = Wq + (size_t)am * CC;
            else if (am < 64)  wrow = Wk + (size_t)(am - 32) * CC;
            else               wrow = Wv + (size_t)(am - 64) * CC;
#pragma unroll
            for (int g = 0; g < 8; g++) {
                f4v f0 = *reinterpret_cast<const f4v*>(wrow + kseg + g * 8);
                f4v f1 = *reinterpret_cast<const f4v*>(wrow + kseg + g * 8 + 4);
                s8v p;
                p[0] = (short)f2bf(f0[0]); p[1] = (short)f2bf(f0[1]);
                p[2] = (short)f2bf(f0[2]); p[3] = (short)f2bf(f0[3]);
                p[4] = (short)f2bf(f1[0]); p[5] = (short)f2bf(f1[1]);
                p[6] = (short)f2bf(f1[2]); p[7] = (short)f2bf(f1[3]);
                *reinterpret_cast<s8v*>(&As[arow * 264 + kseg + g * 8]) = p;
            }
        }
        __syncthreads();

        // ---- compute this m-tile: acc[mt] over K=256 ----
        f4v acc[4];
#pragma unroll
        for (int i = 0; i < 4; i++) acc[i] = (f4v){0.f, 0.f, 0.f, 0.f};
#pragma unroll
        for (int h = 0; h < 8; h++) {
            s8v a[4];
#pragma unroll
            for (int mt = 0; mt < 4; mt++)
                a[mt] = *reinterpret_cast<const s8v*>(
                    &As[(mt * 16 + lq) * 264 + h * 32 + quad * 8]);
#pragma unroll
            for (int mt = 0; mt < 4; mt++)
                acc[mt] = __builtin_amdgcn_mfma_f32_16x16x32_bf16(
                    a[mt], bb[h], acc[mt], 0, 0, 0);
        }

        // ---- epilogue. D: col(n)=lq, row=quad*4+r ----
        if (mten == 0) {
            // q (mt 0,1) and k (mt 2,3): 4 consecutive channels per lane -> packed b64
#pragma unroll
            for (int mt = 0; mt < 2; mt++) {
                int ck = mt * 16 + quad * 4;
                float v0 = (acc[mt][0] + bq[ck + 0]) * L2E;
                float v1 = (acc[mt][1] + bq[ck + 1]) * L2E;
                float v2 = (acc[mt][2] + bq[ck + 2]) * L2E;
                float v3 = (acc[mt][3] + bq[ck + 3]) * L2E;
                u2v w;
                w[0] = pkbf_rne(v0, v1);
                w[1] = pkbf_rne(v2, v3);
                *reinterpret_cast<u2v*>(qw + ((size_t)b * NN + n) * CKD + ck) = w;
            }
#pragma unroll
            for (int mt = 0; mt < 2; mt++) {
                int ck = mt * 16 + quad * 4;
                float v0 = acc[mt + 2][0] + bk[ck + 0];
                float v1 = acc[mt + 2][1] + bk[ck + 1];
                float v2 = acc[mt + 2][2] + bk[ck + 2];
                float v3 = acc[mt + 2][3] + bk[ck + 3];
                u2v w;
                w[0] = pkbf_rne(v0, v1);
                w[1] = pkbf_rne(v2, v3);
                *reinterpret_cast<u2v*>(kw + ((size_t)b * NN + n) * CKD + ck) = w;
            }
        } else {
            // v rows: c = m0-64 + mt*16 + quad*4 + r (layout [c][n], n-coalesced)
#pragma unroll
            for (int mt = 0; mt < 4; mt++)
#pragma unroll
                for (int r = 0; r < 4; r++) {
                    int c = (m0 - 64) + mt * 16 + quad * 4 + r;
                    vw[((size_t)b * CC + c) * NN + n] = f2bf(acc[mt][r] + bv[c]);
                }
        }
    }
}

// ---------------- flash attention (v4 exact revert: known 178 us) ----------------
// Block = 128 q-rows, 8 waves. Wave w: softmax for q rows [w*16,+16) via the K-row-
// permutation trick (P lands in A-frag layout in registers), writes P to LDS (2 b128);
// PV over a PRIVATE 32-channel slice x all 128 q.
//  - V: each wave reads only its 32x64 slice from global -> 32KB/block-kt, read-once.
//  - K: reg-staged into LDS once (4KB/kt, pipeline depth 3).
//  - P: 16KB/kt through LDS (the small tensor takes the broadcast amplification).
// grid (32,16), block 512 = 8 waves; 2 blocks/CU.
__global__ __launch_bounds__(512, 4) void attn(
    const ushort_t* __restrict__ qw, const ushort_t* __restrict__ kw,
    const ushort_t* __restrict__ vw, const float* __restrict__ x,
    const float* __restrict__ alpha, float* __restrict__ out)
{
    __shared__ __align__(16) ushort_t Pl[2][128 * 72];   // 36,864 B  P double buffer
    __shared__ __align__(16) ushort_t Kl[2][64 * 32];    //  8,192 B  K tile double buffer
    __shared__ float lL[128];                            // row denominators

    int b = blockIdx.y;
    int q0 = blockIdx.x * 128;
    int tid = threadIdx.x;
    int wq = tid >> 6, lane = tid & 63;
    int lq = lane & 15, quad = lane >> 4;

    const ushort_t* kbase = kw + (size_t)b * NN * CKD;
    const ushort_t* vbase = vw + (size_t)b * CC * NN;

    // K staging assignment: thread stages 8B of row krow at col kcol
    int krow = tid >> 3;            // 0..63
    int kcol = (tid & 7) * 4;       // shorts
    const ushort_t* ksrc = kbase + (size_t)krow * CKD + kcol;

    // permuted K-row frag offsets in Kl (shorts): kidx = 32(nt>>1)+2(lq&12)+4(nt&1)+(lq&3)
    int kro[4];
#pragma unroll
    for (int nt = 0; nt < 4; nt++)
        kro[nt] = (32 * (nt >> 1) + 2 * (lq & 12) + 4 * (nt & 1) + (lq & 3)) * 32 + quad * 8;

    // V slice rows for this wave: c = wq*32 + ct*16 + lq
    const ushort_t* vrow0 = vbase + (size_t)(wq * 32 + lq) * NN;
    const ushort_t* vrow1 = vbase + (size_t)(wq * 32 + 16 + lq) * NN;

    // Q B-fragment for this wave's 16 rows
    const s8v qf = *reinterpret_cast<const s8v*>(
        qw + ((size_t)b * NN + q0 + wq * 16 + lq) * CKD + quad * 8);

    f4v acc[8][2];
#pragma unroll
    for (int i = 0; i < 8; i++) {
        acc[i][0] = (f4v){0.f, 0.f, 0.f, 0.f};
        acc[i][1] = (f4v){0.f, 0.f, 0.f, 0.f};
    }
    float srow = 0.f;

    // ---- prologue: stage K[0],K[1]; prefetch K[2] + V[0] frags ----
    u2v k0 = *reinterpret_cast<const u2v*>(ksrc);
    u2v k1 = *reinterpret_cast<const u2v*>(ksrc + (size_t)64 * CKD);
    u2v kst = *reinterpret_cast<const u2v*>(ksrc + (size_t)128 * CKD);
    s8v v00 = *reinterpret_cast<const s8v*>(vrow0 + quad * 8);
    s8v v01 = *reinterpret_cast<const s8v*>(vrow0 + 32 + quad * 8);
    s8v v10 = *reinterpret_cast<const s8v*>(vrow1 + quad * 8);
    s8v v11 = *reinterpret_cast<const s8v*>(vrow1 + 32 + quad * 8);
    *reinterpret_cast<u2v*>(&Kl[0][krow * 32 + kcol]) = k0;
    *reinterpret_cast<u2v*>(&Kl[1][krow * 32 + kcol]) = k1;
    __syncthreads();

    for (int kt = 0; kt < 64; kt++) {
        const int cur = kt & 1;

        // ---- QK^T from Kl[cur]; P in-register via permuted rows ----
        s8v pa0, pa1;
        {
            s8v kf0 = *reinterpret_cast<const s8v*>(&Kl[cur][kro[0]]);
            s8v kf1 = *reinterpret_cast<const s8v*>(&Kl[cur][kro[1]]);
            f4v sA = __builtin_amdgcn_mfma_f32_16x16x32_bf16(kf0, qf, (f4v){0.f,0.f,0.f,0.f}, 0, 0, 0);
            f4v sB = __builtin_amdgcn_mfma_f32_16x16x32_bf16(kf1, qf, (f4v){0.f,0.f,0.f,0.f}, 0, 0, 0);
            s8v kf2 = *reinterpret_cast<const s8v*>(&Kl[cur][kro[2]]);
            s8v kf3 = *reinterpret_cast<const s8v*>(&Kl[cur][kro[3]]);
            f4v sC = __builtin_amdgcn_mfma_f32_16x16x32_bf16(kf2, qf, (f4v){0.f,0.f,0.f,0.f}, 0, 0, 0);
            f4v sD = __builtin_amdgcn_mfma_f32_16x16x32_bf16(kf3, qf, (f4v){0.f,0.f,0.f,0.f}, 0, 0, 0);
            float a0 = exp2_hw(sA[0]), a1 = exp2_hw(sA[1]), a2 = exp2_hw(sA[2]), a3 = exp2_hw(sA[3]);
            float b0 = exp2_hw(sB[0]), b1 = exp2_hw(sB[1]), b2 = exp2_hw(sB[2]), b3 = exp2_hw(sB[3]);
            srow += ((a0 + a1) + (a2 + a3)) + ((b0 + b1) + (b2 + b3));
            union { u4v u; s8v s; } t0;
            t0.u[0] = pkbf(a0, a1); t0.u[1] = pkbf(a2, a3);
            t0.u[2] = pkbf(b0, b1); t0.u[3] = pkbf(b2, b3);
            pa0 = t0.s;
            float c0 = exp2_hw(sC[0]), c1 = exp2_hw(sC[1]), c2 = exp2_hw(sC[2]), c3 = exp2_hw(sC[3]);
            float d0 = exp2_hw(sD[0]), d1 = exp2_hw(sD[1]), d2 = exp2_hw(sD[2]), d3 = exp2_hw(sD[3]);
            srow += ((c0 + c1) + (c2 + c3)) + ((d0 + d1) + (d2 + d3));
            union { u4v u; s8v s; } t1;
            t1.u[0] = pkbf(c0, c1); t1.u[1] = pkbf(c2, c3);
            t1.u[2] = pkbf(d0, d1); t1.u[3] = pkbf(d2, d3);
            pa1 = t1.s;
        }

        // publish P (same (row,col) the A-frag reads use -> identity round-trip)
        {
            int prow = (wq * 16 + lq) * 72;
            *reinterpret_cast<s8v*>(&Pl[cur][prow + quad * 8]) = pa0;
            *reinterpret_cast<s8v*>(&Pl[cur][prow + 32 + quad * 8]) = pa1;
        }

        __syncthreads();
        __builtin_amdgcn_sched_barrier(0);

        // stage K[kt+2] -> Kl[cur] (reads of Kl[cur] finished pre-barrier; next read kt+2)
        *reinterpret_cast<u2v*>(&Kl[cur][krow * 32 + kcol]) = kst;

        // ---- PV: O += P V^T over this wave's 32-c slice, all 128 q ----
        __builtin_amdgcn_s_setprio(1);
#pragma unroll
        for (int qt = 0; qt < 8; qt++) {
            s8v pA0 = *reinterpret_cast<const s8v*>(&Pl[cur][(qt * 16 + lq) * 72 + quad * 8]);
            s8v pA1 = *reinterpret_cast<const s8v*>(&Pl[cur][(qt * 16 + lq) * 72 + 32 + quad * 8]);
            acc[qt][0] = __builtin_amdgcn_mfma_f32_16x16x32_bf16(pA0, v00, acc[qt][0], 0, 0, 0);
            acc[qt][0] = __builtin_amdgcn_mfma_f32_16x16x32_bf16(pA1, v01, acc[qt][0], 0, 0, 0);
            acc[qt][1] = __builtin_amdgcn_mfma_f32_16x16x32_bf16(pA0, v10, acc[qt][1], 0, 0, 0);
            acc[qt][1] = __builtin_amdgcn_mfma_f32_16x16x32_bf16(pA1, v11, acc[qt][1], 0, 0, 0);
        }
        __builtin_amdgcn_s_setprio(0);

        // ---- next-tile loads (cover: next QK+exp+P-write+barrier) ----
        {
            int kbn = (kt + 1 < 64 ? kt + 1 : 63) * 64;
            v00 = *reinterpret_cast<const s8v*>(vrow0 + kbn + quad * 8);
            v01 = *reinterpret_cast<const s8v*>(vrow0 + kbn + 32 + quad * 8);
            v10 = *reinterpret_cast<const s8v*>(vrow1 + kbn + quad * 8);
            v11 = *reinterpret_cast<const s8v*>(vrow1 + kbn + 32 + quad * 8);
            int kn = (kt + 3 < 64 ? kt + 3 : 63) * 64;
            kst = *reinterpret_cast<const u2v*>(ksrc + (size_t)kn * CKD);
        }
    }

    // ---- row sums: reduce across quads; share per-wave via LDS ----
    srow += __shfl_xor(srow, 16, 64);
    srow += __shfl_xor(srow, 32, 64);
    if (quad == 0) lL[wq * 16 + lq] = srow;
    __syncthreads();

    // ---- epilogue: out = alpha * (O / l) + x ----
    float a0 = alpha[0];
#pragma unroll
    for (int qt = 0; qt < 8; qt++) {
        float li[4];
#pragma unroll
        for (int r = 0; r < 4; r++) li[r] = 1.0f / lL[qt * 16 + quad * 4 + r];
#pragma unroll
        for (int ct = 0; ct < 2; ct++) {
            int c = wq * 32 + ct * 16 + lq;
            size_t idx = ((size_t)b * CC + c) * NN + q0 + qt * 16 + quad * 4;
            f4v xv = *reinterpret_cast<const f4v*>(x + idx);
            f4v o;
#pragma unroll
            for (int r = 0; r < 4; r++) o[r] = a0 * (acc[qt][ct][r] * li[r]) + xv[r];
            *reinterpret_cast<f4v*>(out + idx) = o;
        }
    }
}

extern "C" void kernel_launch(void* const* d_in, const int* in_sizes, int n_in,
                              void* d_out, int out_size, void* d_ws, size_t ws_size,
                              hipStream_t stream) {
    (void)in_sizes; (void)n_in; (void)out_size; (void)ws_size;
    const float* x     = (const float*)d_in[0];
    const float* Wq    = (const float*)d_in[1];
    const float* bq    = (const float*)d_in[2];
    const float* Wk    = (const float*)d_in[3];
    const float* bk    = (const float*)d_in[4];
    const float* Wv    = (const float*)d_in[5];
    const float* bv    = (const float*)d_in[6];
    const float* alpha = (const float*)d_in[7];
    float* out = (float*)d_out;

    // Workspace: q (4MB) | k (4MB) | v (32MB), all bf16
    char* ws = (char*)d_ws;
    ushort_t* qw = (ushort_t*)ws;
    ushort_t* kw = (ushort_t*)(ws + (size_t)BN * NN * CKD * 2);
    ushort_t* vw = (ushort_t*)(ws + (size_t)2 * BN * NN * CKD * 2);

    proj_all<<<dim3(64, BN), 256, 0, stream>>>(x, Wq, bq, Wk, bk, Wv, bv, qw, kw, vw);
    attn    <<<dim3(NN / 128, BN), 512, 0, stream>>>(qw, kw, vw, x, alpha, out);
}